// Round 7
// baseline (70.916 us; speedup 1.0000x reference)
//
#include <hip/hip_runtime.h>
#include <hip/hip_fp16.h>
#include <stdint.h>

#define H 1024
#define BATCH 2048
#define KDIM 2048   // input + hidden concatenated
#define NDIM 4096   // 4 gates
#define EPS 1e-5f

#define BM 128
#define BN 256
#define BK 32

typedef __attribute__((ext_vector_type(8))) short bf16x8;
typedef __attribute__((ext_vector_type(4))) float f32x4;

#define FENCE asm volatile("" ::: "memory")

__device__ __forceinline__ unsigned short f2bf(float f) {
  uint32_t u = __float_as_uint(f);
  u += 0x7FFFu + ((u >> 16) & 1u);
  return (unsigned short)(u >> 16);
}

__device__ __forceinline__ float fast_sig(float x) {
  x = fminf(30.f, fmaxf(-30.f, x));
  float e = __expf(x);
  return e / (e + 1.f);
}

__device__ __forceinline__ float fast_tanh(float x) {
  x = fminf(15.f, fmaxf(-15.f, x));
  float e = __expf(2.f * x);
  return (e - 1.f) / (e + 1.f);
}

// ---------------- pack: f32 -> bf16, concat along K ----------------
__global__ __launch_bounds__(256) void pack_kernel(
    const float* __restrict__ x, const float* __restrict__ h,
    const float* __restrict__ Wih, const float* __restrict__ Whh,
    unsigned short* __restrict__ A, unsigned short* __restrict__ B) {
  int u = blockIdx.x * 256 + threadIdx.x;
  const int unitsA = BATCH * KDIM / 4;
  const float* src;
  unsigned short* dst;
  if (u < unitsA) {
    int m = u >> 9;
    int kv = (u & 511) << 2;
    src = (kv < H) ? (x + (size_t)m * H + kv) : (h + (size_t)m * H + (kv - H));
    dst = A + (size_t)m * KDIM + kv;
  } else {
    int v = u - unitsA;
    int m = v >> 9;
    int kv = (v & 511) << 2;
    src = (kv < H) ? (Wih + (size_t)m * H + kv) : (Whh + (size_t)m * H + (kv - H));
    dst = B + (size_t)m * KDIM + kv;
  }
  float4 f = *(const float4*)src;
  ushort4 o;
  o.x = f2bf(f.x);
  o.y = f2bf(f.y);
  o.z = f2bf(f.z);
  o.w = f2bf(f.w);
  *(ushort4*)dst = o;
}

// -------- GEMM: 128x256, BK=32, fat per-wave tiles (64x128), 2-phase dbuf ----
__device__ __forceinline__ void load_lds16(const void* g, void* l) {
  __builtin_amdgcn_global_load_lds(
      (const __attribute__((address_space(1))) void*)g,
      (__attribute__((address_space(3))) void*)l, 16, 0, 0);
}

__global__ __launch_bounds__(256, 2) void gemm_kernel(
    const unsigned short* __restrict__ A,  // 2048 x 2048 bf16
    const unsigned short* __restrict__ B,  // 4096 x 2048 bf16 (B^T layout)
    __half* __restrict__ P0, __half* __restrict__ P1) {
  __shared__ unsigned short sA[2][BM * BK];  // 2 x 8 KB
  __shared__ unsigned short sB[2][BN * BK];  // 2 x 16 KB

  const int tid = threadIdx.x;
  const int wave = tid >> 6;
  const int lane = tid & 63;
  const int m0 = blockIdx.y * BM;
  const int n0 = blockIdx.x * BN;
  const int kbase = blockIdx.z * (KDIM / 2);
  __half* __restrict__ P = blockIdx.z ? P1 : P0;
  const int wr = (wave >> 1) * 64;   // A-rows quadrant (64 rows/wave)
  const int wc = (wave & 1) * 128;   // B-cols quadrant (128 cols/wave)

  const int frow = lane & 15;
  const int kc = lane >> 4;  // logical 16B k-chunk 0..3

  // staging: per pass 16 rows; lane -> (row = p*16 + (lane>>2), phys chunk = lane&3)
  // LDS holds logical chunk (phys ^ (row&3)); row&3 == (lane>>2)&3 here.
  const int srow = lane >> 2;                         // 0..15 within pass
  const int schoff = (((lane & 3) ^ (srow & 3)) << 3);  // logical elem offset
  // read side: phys chunk = kc ^ (row&3); row&3 == frow&3 for all frag rows
  const int roff = frow * 64 + (((kc ^ (frow & 3)) & 3) << 4);  // bytes

  f32x4 acc[4][8] = {};

  const int NT = (KDIM / 2) / BK;  // 32

  auto stage = [&](int t, int buf) {
    const int k0 = kbase + t * BK;
    // A: rows wave*32 + p*16 + srow  (2 passes, 32 rows/wave)
#pragma unroll
    for (int p = 0; p < 2; ++p) {
      const int row = wave * 32 + p * 16 + srow;
      load_lds16(A + (size_t)(m0 + row) * KDIM + k0 + schoff,
                 (char*)sA[buf] + (wave * 32 + p * 16) * 64);
    }
    // B: rows wave*64 + p*16 + srow  (4 passes, 64 rows/wave)
#pragma unroll
    for (int p = 0; p < 4; ++p) {
      const int row = wave * 64 + p * 16 + srow;
      load_lds16(B + (size_t)(n0 + row) * KDIM + k0 + schoff,
                 (char*)sB[buf] + (wave * 64 + p * 16) * 64);
    }
  };

  stage(0, 0);

  for (int t = 0; t < NT; ++t) {
    const int cur = t & 1;
    if (t + 1 < NT) {
      stage(t + 1, cur ^ 1);  // buffer freed by end-barrier of t-1
      asm volatile("s_waitcnt vmcnt(6)" ::: "memory");  // own stage(t) landed
    } else {
      asm volatile("s_waitcnt vmcnt(0)" ::: "memory");
    }
    __builtin_amdgcn_s_barrier();  // all waves' stage(t) portions landed
    FENCE;

    bf16x8 a[4], b[8];
#pragma unroll
    for (int i = 0; i < 4; ++i)
      a[i] = *(const bf16x8*)((const char*)sA[cur] + (wr + i * 16) * 64 + roff);
#pragma unroll
    for (int n = 0; n < 8; ++n)
      b[n] = *(const bf16x8*)((const char*)sB[cur] + (wc + n * 16) * 64 + roff);

    __builtin_amdgcn_s_setprio(1);
#pragma unroll
    for (int i = 0; i < 4; ++i)
#pragma unroll
      for (int n = 0; n < 8; ++n)
        acc[i][n] =
            __builtin_amdgcn_mfma_f32_16x16x32_bf16(a[i], b[n], acc[i][n], 0, 0, 0);
    __builtin_amdgcn_s_setprio(0);

    FENCE;
    __builtin_amdgcn_s_barrier();  // all waves done reading buf[cur]
  }

  // store fp16 partials
  const int crow = (lane >> 4) << 2;
  const int ccol = lane & 15;
#pragma unroll
  for (int i = 0; i < 4; ++i)
#pragma unroll
    for (int n = 0; n < 8; ++n) {
      __half* cp = P + (size_t)(m0 + wr + i * 16 + crow) * NDIM + (n0 + wc + n * 16 + ccol);
#pragma unroll
      for (int r = 0; r < 4; ++r) cp[(size_t)r * NDIM] = __float2half(acc[i][n][r]);
    }
}

// ---------------- epilogue: sum partials + gates + c update + LN + h --------
__global__ __launch_bounds__(256) void epilogue_kernel(
    const __half* __restrict__ P0, const __half* __restrict__ P1,
    const float* __restrict__ c_in,
    const float* __restrict__ b_ih, const float* __restrict__ b_hh,
    const float* __restrict__ ln_w, const float* __restrict__ ln_b,
    float* __restrict__ h_out, float* __restrict__ c_out) {
  const int m = blockIdx.x;
  const int t = threadIdx.x;
  const int j = t << 2;
  const __half* r0 = P0 + (size_t)m * NDIM;
  const __half* r1 = P1 + (size_t)m * NDIM;

  float pre[4][4];
#pragma unroll
  for (int g = 0; g < 4; ++g) {
    ushort4 u0 = *(const ushort4*)(r0 + g * H + j);
    ushort4 u1 = *(const ushort4*)(r1 + g * H + j);
    float4 bi = *(const float4*)(b_ih + g * H + j);
    float4 bh = *(const float4*)(b_hh + g * H + j);
    pre[g][0] = __half2float(*(__half*)&u0.x) + __half2float(*(__half*)&u1.x) + bi.x + bh.x;
    pre[g][1] = __half2float(*(__half*)&u0.y) + __half2float(*(__half*)&u1.y) + bi.y + bh.y;
    pre[g][2] = __half2float(*(__half*)&u0.z) + __half2float(*(__half*)&u1.z) + bi.z + bh.z;
    pre[g][3] = __half2float(*(__half*)&u0.w) + __half2float(*(__half*)&u1.w) + bi.w + bh.w;
  }
  float4 ci = *(const float4*)(c_in + (size_t)m * H + j);

  float cr[4], vo[4];
  float s = 0.f, q = 0.f;
#pragma unroll
  for (int r = 0; r < 4; ++r) {
    float iv = fast_sig(pre[0][r]);
    float fv = fast_sig(pre[1][r]);
    float ov = fast_sig(pre[2][r]);
    float gv = fast_tanh(pre[3][r]);
    float cv = ((const float*)&ci)[r] * fv + iv * gv;
    cr[r] = cv;
    vo[r] = ov;
    s += cv;
    q += cv * cv;
  }

#pragma unroll
  for (int off = 32; off > 0; off >>= 1) {
    s += __shfl_xor(s, off);
    q += __shfl_xor(q, off);
  }
  __shared__ float red[8];
  const int wv = t >> 6, ln = t & 63;
  if (ln == 0) {
    red[wv] = s;
    red[wv + 4] = q;
  }
  __syncthreads();
  s = red[0] + red[1] + red[2] + red[3];
  q = red[4] + red[5] + red[6] + red[7];
  const float mu = s * (1.f / H);
  const float var = q * (1.f / H) - mu * mu;
  const float rstd = rsqrtf(var + EPS);

  float4 lw = *(const float4*)(ln_w + j);
  float4 lb = *(const float4*)(ln_b + j);
  float4 hov, cov;
#pragma unroll
  for (int r = 0; r < 4; ++r) {
    float cn = (cr[r] - mu) * rstd * ((const float*)&lw)[r] + ((const float*)&lb)[r];
    ((float*)&cov)[r] = cn;
    ((float*)&hov)[r] = vo[r] * fast_tanh(cn);
  }
  *(float4*)(h_out + (size_t)m * H + j) = hov;
  *(float4*)(c_out + (size_t)m * H + j) = cov;
}

extern "C" void kernel_launch(void* const* d_in, const int* in_sizes, int n_in,
                              void* d_out, int out_size, void* d_ws, size_t ws_size,
                              hipStream_t stream) {
  const float* x = (const float*)d_in[0];
  const float* h = (const float*)d_in[1];
  const float* c = (const float*)d_in[2];
  const float* Wih = (const float*)d_in[3];
  const float* b_ih = (const float*)d_in[4];
  const float* Whh = (const float*)d_in[5];
  const float* b_hh = (const float*)d_in[6];
  const float* ln_w = (const float*)d_in[7];
  const float* ln_b = (const float*)d_in[8];

  unsigned short* A = (unsigned short*)d_ws;                                      // 8 MB
  unsigned short* B = (unsigned short*)((char*)d_ws + (size_t)BATCH * KDIM * 2);  // 16 MB
  char* pbase = (char*)d_ws + (size_t)BATCH * KDIM * 2 + (size_t)NDIM * KDIM * 2;
  __half* P0 = (__half*)pbase;                               // 16 MB
  __half* P1 = (__half*)(pbase + (size_t)BATCH * NDIM * 2);  // 16 MB

  float* h_out = (float*)d_out;
  float* c_out = (float*)d_out + (size_t)BATCH * H;

  pack_kernel<<<12288, 256, 0, stream>>>(x, h, Wih, Whh, A, B);
  dim3 g(NDIM / BN, BATCH / BM, 2);
  gemm_kernel<<<g, 256, 0, stream>>>(A, B, P0, P1);
  epilogue_kernel<<<BATCH, 256, 0, stream>>>(P0, P1, c, b_ih, b_hh, ln_w, ln_b, h_out, c_out);
}

// Round 8
// 52.837 us; speedup vs baseline: 1.3422x; 1.3422x over previous
//
#include <hip/hip_runtime.h>
#include <hip/hip_fp16.h>
#include <stdint.h>

#define H 1024
#define BATCH 2048
#define KDIM 2048   // input + hidden concatenated (elements)
#define NDIM 4096   // 4 gates
#define EPS 1e-5f

#define BM 128
#define BN 128
#define BK 64  // i8 elements per K-step

typedef __attribute__((ext_vector_type(4))) int i32x4;

#define FENCE asm volatile("" ::: "memory")

__device__ __forceinline__ float fast_sig(float x) {
  x = fminf(30.f, fmaxf(-30.f, x));
  float e = __expf(x);
  return e / (e + 1.f);
}

__device__ __forceinline__ float fast_tanh(float x) {
  x = fminf(15.f, fmaxf(-15.f, x));
  float e = __expf(2.f * x);
  return (e - 1.f) / (e + 1.f);
}

// ---------------- quant: per-row max-scale int8, concat along K ----------------
// rows 0..2047: A row r = [x[r,:] | h[r,:]]  -> Ai8, sA
// rows 2048..6143: B row r = [Wih[r,:] | Whh[r,:]] -> Bi8, sB
__global__ __launch_bounds__(256) void quant_kernel(
    const float* __restrict__ x, const float* __restrict__ h,
    const float* __restrict__ Wih, const float* __restrict__ Whh,
    char* __restrict__ Ai8, char* __restrict__ Bi8,
    float* __restrict__ sA, float* __restrict__ sB) {
  const int r = blockIdx.x;
  const int t = threadIdx.x;
  const float* s0;
  const float* s1;
  char* dst;
  float* sOut;
  if (r < BATCH) {
    s0 = x + (size_t)r * H;
    s1 = h + (size_t)r * H;
    dst = Ai8 + (size_t)r * KDIM;
    sOut = sA + r;
  } else {
    const int rb = r - BATCH;
    s0 = Wih + (size_t)rb * H;
    s1 = Whh + (size_t)rb * H;
    dst = Bi8 + (size_t)rb * KDIM;
    sOut = sB + rb;
  }
  const float* src = (t < 128) ? (s0 + t * 8) : (s1 + (t - 128) * 8);
  float4 v0 = *(const float4*)src;
  float4 v1 = *(const float4*)(src + 4);
  float vv[8] = {v0.x, v0.y, v0.z, v0.w, v1.x, v1.y, v1.z, v1.w};

  float m = 0.f;
#pragma unroll
  for (int i = 0; i < 8; ++i) m = fmaxf(m, fabsf(vv[i]));
#pragma unroll
  for (int off = 32; off > 0; off >>= 1) m = fmaxf(m, __shfl_xor(m, off));
  __shared__ float red[4];
  if ((t & 63) == 0) red[t >> 6] = m;
  __syncthreads();
  m = fmaxf(fmaxf(red[0], red[1]), fmaxf(red[2], red[3]));
  m = fmaxf(m, 1e-20f);
  if (t == 0) *sOut = m * (1.0f / 127.0f);
  const float inv = 127.0f / m;

  char out[8];
#pragma unroll
  for (int i = 0; i < 8; ++i) {
    int qi = (int)rintf(vv[i] * inv);
    qi = max(-127, min(127, qi));
    out[i] = (char)qi;
  }
  *(int2*)(dst + t * 8) = *(const int2*)out;
}

// ---------------- GEMM: int8 MFMA, R2 chassis (single-buf, split-K=2) -------
__device__ __forceinline__ void load_lds16(const void* g, void* l) {
  __builtin_amdgcn_global_load_lds(
      (const __attribute__((address_space(1))) void*)g,
      (__attribute__((address_space(3))) void*)l, 16, 0, 0);
}

__global__ __launch_bounds__(256, 4) void gemm_kernel(
    const char* __restrict__ A8,  // 2048 x 2048 i8
    const char* __restrict__ B8,  // 4096 x 2048 i8 (B^T layout)
    const float* __restrict__ sA, const float* __restrict__ sB,
    __half* __restrict__ P0, __half* __restrict__ P1) {
  __shared__ char sAt[BM * BK];  // 8 KB
  __shared__ char sBt[BN * BK];  // 8 KB

  const int tid = threadIdx.x;
  const int wave = tid >> 6;
  const int lane = tid & 63;
  const int m0 = blockIdx.y * BM;
  const int n0 = blockIdx.x * BN;
  const int kbase = blockIdx.z * (KDIM / 2);
  __half* __restrict__ P = blockIdx.z ? P1 : P0;
  const int wr = (wave >> 1) * 64;
  const int wc = (wave & 1) * 64;

  const int frow = lane & 15;
  const int kc = lane >> 4;  // 16B chunk (16 i8) index 0..3

  // stage: instr covers 16 rows: row = grp*16 + (lane>>2); phys chunk = lane&3
  // swizzle s(row) = (row>>1)&3 -> within instr: ((lane>>3)&3)
  const int ssrcoff = (((lane & 3) ^ ((lane >> 3) & 3)) << 4);  // source elem off
  // read: phys chunk = kc ^ ((row>>1)&3); row>>1&3 == (frow>>1)&3 for all frags
  const int roff = frow * 64 + ((kc ^ ((frow >> 1) & 3)) << 4);  // byte offset

  i32x4 acc[4][4] = {};

  const int NT = (KDIM / 2) / BK;  // 16

  for (int t = 0; t < NT; ++t) {
    const int k0 = kbase + t * BK;
#pragma unroll
    for (int p = 0; p < 2; ++p) {
      const int rg = wave * 32 + p * 16;  // row group base (16 rows/instr)
      load_lds16(A8 + (size_t)(m0 + rg + (lane >> 2)) * KDIM + k0 + ssrcoff,
                 sAt + rg * 64);
      load_lds16(B8 + (size_t)(n0 + rg + (lane >> 2)) * KDIM + k0 + ssrcoff,
                 sBt + rg * 64);
    }
    asm volatile("s_waitcnt vmcnt(0)" ::: "memory");
    __syncthreads();

    i32x4 a[4], b[4];
#pragma unroll
    for (int i = 0; i < 4; ++i) {
      a[i] = *(const i32x4*)(sAt + (wr + i * 16) * 64 + roff);
      b[i] = *(const i32x4*)(sBt + (wc + i * 16) * 64 + roff);
    }
#pragma unroll
    for (int i = 0; i < 4; ++i)
#pragma unroll
      for (int j = 0; j < 4; ++j)
        acc[i][j] = __builtin_amdgcn_mfma_i32_16x16x64_i8(a[i], b[j], acc[i][j], 0, 0, 0);

    __syncthreads();
  }

  // dequant + store fp16 partials
  const int crow = (lane >> 4) << 2;
  const int ccol = lane & 15;
  float scA[4][4], scB[4];
#pragma unroll
  for (int j = 0; j < 4; ++j) scB[j] = sB[n0 + wc + j * 16 + ccol];
#pragma unroll
  for (int i = 0; i < 4; ++i)
#pragma unroll
    for (int r = 0; r < 4; ++r) scA[i][r] = sA[m0 + wr + i * 16 + crow + r];

#pragma unroll
  for (int i = 0; i < 4; ++i)
#pragma unroll
    for (int j = 0; j < 4; ++j) {
      __half* cp = P + (size_t)(m0 + wr + i * 16 + crow) * NDIM + (n0 + wc + j * 16 + ccol);
#pragma unroll
      for (int r = 0; r < 4; ++r)
        cp[(size_t)r * NDIM] = __float2half((float)acc[i][j][r] * scA[i][r] * scB[j]);
    }
}

// ---------------- epilogue: sum partials + gates + c update + LN + h --------
__global__ __launch_bounds__(256) void epilogue_kernel(
    const __half* __restrict__ P0, const __half* __restrict__ P1,
    const float* __restrict__ c_in,
    const float* __restrict__ b_ih, const float* __restrict__ b_hh,
    const float* __restrict__ ln_w, const float* __restrict__ ln_b,
    float* __restrict__ h_out, float* __restrict__ c_out) {
  const int m = blockIdx.x;
  const int t = threadIdx.x;
  const int j = t << 2;
  const __half* r0 = P0 + (size_t)m * NDIM;
  const __half* r1 = P1 + (size_t)m * NDIM;

  float pre[4][4];
#pragma unroll
  for (int g = 0; g < 4; ++g) {
    ushort4 u0 = *(const ushort4*)(r0 + g * H + j);
    ushort4 u1 = *(const ushort4*)(r1 + g * H + j);
    float4 bi = *(const float4*)(b_ih + g * H + j);
    float4 bh = *(const float4*)(b_hh + g * H + j);
    pre[g][0] = __half2float(*(__half*)&u0.x) + __half2float(*(__half*)&u1.x) + bi.x + bh.x;
    pre[g][1] = __half2float(*(__half*)&u0.y) + __half2float(*(__half*)&u1.y) + bi.y + bh.y;
    pre[g][2] = __half2float(*(__half*)&u0.z) + __half2float(*(__half*)&u1.z) + bi.z + bh.z;
    pre[g][3] = __half2float(*(__half*)&u0.w) + __half2float(*(__half*)&u1.w) + bi.w + bh.w;
  }
  float4 ci = *(const float4*)(c_in + (size_t)m * H + j);

  float cr[4], vo[4];
  float s = 0.f, q = 0.f;
#pragma unroll
  for (int r = 0; r < 4; ++r) {
    float iv = fast_sig(pre[0][r]);
    float fv = fast_sig(pre[1][r]);
    float ov = fast_sig(pre[2][r]);
    float gv = fast_tanh(pre[3][r]);
    float cv = ((const float*)&ci)[r] * fv + iv * gv;
    cr[r] = cv;
    vo[r] = ov;
    s += cv;
    q += cv * cv;
  }

#pragma unroll
  for (int off = 32; off > 0; off >>= 1) {
    s += __shfl_xor(s, off);
    q += __shfl_xor(q, off);
  }
  __shared__ float red[8];
  const int wv = t >> 6, ln = t & 63;
  if (ln == 0) {
    red[wv] = s;
    red[wv + 4] = q;
  }
  __syncthreads();
  s = red[0] + red[1] + red[2] + red[3];
  q = red[4] + red[5] + red[6] + red[7];
  const float mu = s * (1.f / H);
  const float var = q * (1.f / H) - mu * mu;
  const float rstd = rsqrtf(var + EPS);

  float4 lw = *(const float4*)(ln_w + j);
  float4 lb = *(const float4*)(ln_b + j);
  float4 hov, cov;
#pragma unroll
  for (int r = 0; r < 4; ++r) {
    float cn = (cr[r] - mu) * rstd * ((const float*)&lw)[r] + ((const float*)&lb)[r];
    ((float*)&cov)[r] = cn;
    ((float*)&hov)[r] = vo[r] * fast_tanh(cn);
  }
  *(float4*)(h_out + (size_t)m * H + j) = hov;
  *(float4*)(c_out + (size_t)m * H + j) = cov;
}

extern "C" void kernel_launch(void* const* d_in, const int* in_sizes, int n_in,
                              void* d_out, int out_size, void* d_ws, size_t ws_size,
                              hipStream_t stream) {
  const float* x = (const float*)d_in[0];
  const float* h = (const float*)d_in[1];
  const float* c = (const float*)d_in[2];
  const float* Wih = (const float*)d_in[3];
  const float* b_ih = (const float*)d_in[4];
  const float* Whh = (const float*)d_in[5];
  const float* b_hh = (const float*)d_in[6];
  const float* ln_w = (const float*)d_in[7];
  const float* ln_b = (const float*)d_in[8];

  char* Ai8 = (char*)d_ws;                                   // 4 MB @ 0
  char* Bi8 = (char*)d_ws + (4u << 20);                      // 8 MB @ 4M
  float* sA = (float*)((char*)d_ws + (12u << 20));           // 8 KB @ 12M
  float* sB = (float*)((char*)d_ws + (12u << 20) + 32768);   // 16 KB
  __half* P0 = (__half*)((char*)d_ws + (16u << 20));         // 16 MB @ 16M
  __half* P1 = (__half*)((char*)d_ws + (32u << 20));         // 16 MB @ 32M

  float* h_out = (float*)d_out;
  float* c_out = (float*)d_out + (size_t)BATCH * H;

  quant_kernel<<<BATCH + NDIM, 256, 0, stream>>>(x, h, Wih, Whh, Ai8, Bi8, sA, sB);
  dim3 g(NDIM / BN, BATCH / BM, 2);
  gemm_kernel<<<g, 256, 0, stream>>>(Ai8, Bi8, sA, sB, P0, P1);
  epilogue_kernel<<<BATCH, 256, 0, stream>>>(P0, P1, c, b_ih, b_hh, ln_w, ln_b, h_out, c_out);
}

// Round 9
// 48.892 us; speedup vs baseline: 1.4505x; 1.0807x over previous
//
#include <hip/hip_runtime.h>
#include <hip/hip_fp16.h>
#include <stdint.h>

#define H 1024
#define BATCH 2048
#define KDIM 2048   // input + hidden concatenated (elements)
#define NDIM 4096   // 4 gates
#define EPS 1e-5f

#define BM 128
#define BN 128
#define BK 128  // i8 elements per K-step (16 KB per matrix tile)

typedef __attribute__((ext_vector_type(4))) int i32x4;

__device__ __forceinline__ float fast_sig(float x) {
  x = fminf(30.f, fmaxf(-30.f, x));
  float e = __expf(x);
  return e / (e + 1.f);
}

__device__ __forceinline__ float fast_tanh(float x) {
  x = fminf(15.f, fmaxf(-15.f, x));
  float e = __expf(2.f * x);
  return (e - 1.f) / (e + 1.f);
}

// ---------------- quant: per-row max-scale int8, concat along K ----------------
__global__ __launch_bounds__(256) void quant_kernel(
    const float* __restrict__ x, const float* __restrict__ h,
    const float* __restrict__ Wih, const float* __restrict__ Whh,
    char* __restrict__ Ai8, char* __restrict__ Bi8,
    float* __restrict__ sA, float* __restrict__ sB) {
  const int r = blockIdx.x;
  const int t = threadIdx.x;
  const float* s0;
  const float* s1;
  char* dst;
  float* sOut;
  if (r < BATCH) {
    s0 = x + (size_t)r * H;
    s1 = h + (size_t)r * H;
    dst = Ai8 + (size_t)r * KDIM;
    sOut = sA + r;
  } else {
    const int rb = r - BATCH;
    s0 = Wih + (size_t)rb * H;
    s1 = Whh + (size_t)rb * H;
    dst = Bi8 + (size_t)rb * KDIM;
    sOut = sB + rb;
  }
  const float* src = (t < 128) ? (s0 + t * 8) : (s1 + (t - 128) * 8);
  float4 v0 = *(const float4*)src;
  float4 v1 = *(const float4*)(src + 4);
  float vv[8] = {v0.x, v0.y, v0.z, v0.w, v1.x, v1.y, v1.z, v1.w};

  float m = 0.f;
#pragma unroll
  for (int i = 0; i < 8; ++i) m = fmaxf(m, fabsf(vv[i]));
#pragma unroll
  for (int off = 32; off > 0; off >>= 1) m = fmaxf(m, __shfl_xor(m, off));
  __shared__ float red[4];
  if ((t & 63) == 0) red[t >> 6] = m;
  __syncthreads();
  m = fmaxf(fmaxf(red[0], red[1]), fmaxf(red[2], red[3]));
  m = fmaxf(m, 1e-20f);
  if (t == 0) *sOut = m * (1.0f / 127.0f);
  const float inv = 127.0f / m;

  char out[8];
#pragma unroll
  for (int i = 0; i < 8; ++i) {
    int qi = (int)rintf(vv[i] * inv);
    qi = max(-127, min(127, qi));
    out[i] = (char)qi;
  }
  *(int2*)(dst + t * 8) = *(const int2*)out;
}

// ---------------- GEMM: int8 MFMA, BK=128, NT=8, single-buffer --------------
__device__ __forceinline__ void load_lds16(const void* g, void* l) {
  __builtin_amdgcn_global_load_lds(
      (const __attribute__((address_space(1))) void*)g,
      (__attribute__((address_space(3))) void*)l, 16, 0, 0);
}

__global__ __launch_bounds__(256, 4) void gemm_kernel(
    const char* __restrict__ A8,  // 2048 x 2048 i8
    const char* __restrict__ B8,  // 4096 x 2048 i8 (B^T layout)
    const float* __restrict__ sA, const float* __restrict__ sB,
    __half* __restrict__ P0, __half* __restrict__ P1) {
  __shared__ char sAt[BM * BK];  // 16 KB
  __shared__ char sBt[BN * BK];  // 16 KB

  const int tid = threadIdx.x;
  const int wave = tid >> 6;
  const int lane = tid & 63;
  const int m0 = blockIdx.y * BM;
  const int n0 = blockIdx.x * BN;
  const int kbase = blockIdx.z * (KDIM / 2);
  __half* __restrict__ P = blockIdx.z ? P1 : P0;
  const int wr = (wave >> 1) * 64;
  const int wc = (wave & 1) * 64;

  const int frow = lane & 15;
  const int klane = lane >> 4;  // 0..3

  // stage: instr covers 8 rows (8 x 128B = 1 KB): row = base + (lane>>3),
  // phys chunk = lane&7 (linear dest). Source chunk pre-XORed by row&7:
  const int ssrcoff = (((lane & 7) ^ ((lane >> 3) & 7)) << 4);
  // read: logical chunk kc2 = ks*4 + klane; phys = kc2 ^ (row&7); row&7 = frow&7
  const int rxor = (frow & 7);
  const int rbyteA = frow * BK;  // row base (wr/i added per frag)

  i32x4 acc[4][4] = {};

  const int NT = (KDIM / 2) / BK;  // 8

  for (int t = 0; t < NT; ++t) {
    const int k0 = kbase + t * BK;
#pragma unroll
    for (int p = 0; p < 4; ++p) {
      const int rg = wave * 32 + p * 8;  // 8-row group base
      load_lds16(A8 + (size_t)(m0 + rg + (lane >> 3)) * KDIM + k0 + ssrcoff,
                 sAt + rg * BK);
      load_lds16(B8 + (size_t)(n0 + rg + (lane >> 3)) * KDIM + k0 + ssrcoff,
                 sBt + rg * BK);
    }
    asm volatile("s_waitcnt vmcnt(0)" ::: "memory");
    __syncthreads();

#pragma unroll
    for (int ks = 0; ks < 2; ++ks) {
      const int coff = (((ks * 4 + klane) ^ rxor) << 4);
      i32x4 a[4], b[4];
#pragma unroll
      for (int i = 0; i < 4; ++i) {
        a[i] = *(const i32x4*)(sAt + (wr + i * 16 + frow) * BK + coff);
        b[i] = *(const i32x4*)(sBt + (wc + i * 16 + frow) * BK + coff);
      }
      __builtin_amdgcn_s_setprio(1);
#pragma unroll
      for (int i = 0; i < 4; ++i)
#pragma unroll
        for (int j = 0; j < 4; ++j)
          acc[i][j] =
              __builtin_amdgcn_mfma_i32_16x16x64_i8(a[i], b[j], acc[i][j], 0, 0, 0);
      __builtin_amdgcn_s_setprio(0);
    }

    __syncthreads();
  }

  // dequant + store fp16 partials
  const int crow = (lane >> 4) << 2;
  const int ccol = lane & 15;
  float scA[4][4], scB[4];
#pragma unroll
  for (int j = 0; j < 4; ++j) scB[j] = sB[n0 + wc + j * 16 + ccol];
#pragma unroll
  for (int i = 0; i < 4; ++i)
#pragma unroll
    for (int r = 0; r < 4; ++r) scA[i][r] = sA[m0 + wr + i * 16 + crow + r];

#pragma unroll
  for (int i = 0; i < 4; ++i)
#pragma unroll
    for (int j = 0; j < 4; ++j) {
      __half* cp = P + (size_t)(m0 + wr + i * 16 + crow) * NDIM + (n0 + wc + j * 16 + ccol);
#pragma unroll
      for (int r = 0; r < 4; ++r)
        cp[(size_t)r * NDIM] = __float2half((float)acc[i][j][r] * scA[i][r] * scB[j]);
    }
}

// ---------------- epilogue: sum partials + gates + c update + LN + h --------
__global__ __launch_bounds__(256) void epilogue_kernel(
    const __half* __restrict__ P0, const __half* __restrict__ P1,
    const float* __restrict__ c_in,
    const float* __restrict__ b_ih, const float* __restrict__ b_hh,
    const float* __restrict__ ln_w, const float* __restrict__ ln_b,
    float* __restrict__ h_out, float* __restrict__ c_out) {
  const int m = blockIdx.x;
  const int t = threadIdx.x;
  const int j = t << 2;
  const __half* r0 = P0 + (size_t)m * NDIM;
  const __half* r1 = P1 + (size_t)m * NDIM;

  float pre[4][4];
#pragma unroll
  for (int g = 0; g < 4; ++g) {
    ushort4 u0 = *(const ushort4*)(r0 + g * H + j);
    ushort4 u1 = *(const ushort4*)(r1 + g * H + j);
    float4 bi = *(const float4*)(b_ih + g * H + j);
    float4 bh = *(const float4*)(b_hh + g * H + j);
    pre[g][0] = __half2float(*(__half*)&u0.x) + __half2float(*(__half*)&u1.x) + bi.x + bh.x;
    pre[g][1] = __half2float(*(__half*)&u0.y) + __half2float(*(__half*)&u1.y) + bi.y + bh.y;
    pre[g][2] = __half2float(*(__half*)&u0.z) + __half2float(*(__half*)&u1.z) + bi.z + bh.z;
    pre[g][3] = __half2float(*(__half*)&u0.w) + __half2float(*(__half*)&u1.w) + bi.w + bh.w;
  }
  float4 ci = *(const float4*)(c_in + (size_t)m * H + j);

  float cr[4], vo[4];
  float s = 0.f, q = 0.f;
#pragma unroll
  for (int r = 0; r < 4; ++r) {
    float iv = fast_sig(pre[0][r]);
    float fv = fast_sig(pre[1][r]);
    float ov = fast_sig(pre[2][r]);
    float gv = fast_tanh(pre[3][r]);
    float cv = ((const float*)&ci)[r] * fv + iv * gv;
    cr[r] = cv;
    vo[r] = ov;
    s += cv;
    q += cv * cv;
  }

#pragma unroll
  for (int off = 32; off > 0; off >>= 1) {
    s += __shfl_xor(s, off);
    q += __shfl_xor(q, off);
  }
  __shared__ float red[8];
  const int wv = t >> 6, ln = t & 63;
  if (ln == 0) {
    red[wv] = s;
    red[wv + 4] = q;
  }
  __syncthreads();
  s = red[0] + red[1] + red[2] + red[3];
  q = red[4] + red[5] + red[6] + red[7];
  const float mu = s * (1.f / H);
  const float var = q * (1.f / H) - mu * mu;
  const float rstd = rsqrtf(var + EPS);

  float4 lw = *(const float4*)(ln_w + j);
  float4 lb = *(const float4*)(ln_b + j);
  float4 hov, cov;
#pragma unroll
  for (int r = 0; r < 4; ++r) {
    float cn = (cr[r] - mu) * rstd * ((const float*)&lw)[r] + ((const float*)&lb)[r];
    ((float*)&cov)[r] = cn;
    ((float*)&hov)[r] = vo[r] * fast_tanh(cn);
  }
  *(float4*)(h_out + (size_t)m * H + j) = hov;
  *(float4*)(c_out + (size_t)m * H + j) = cov;
}

extern "C" void kernel_launch(void* const* d_in, const int* in_sizes, int n_in,
                              void* d_out, int out_size, void* d_ws, size_t ws_size,
                              hipStream_t stream) {
  const float* x = (const float*)d_in[0];
  const float* h = (const float*)d_in[1];
  const float* c = (const float*)d_in[2];
  const float* Wih = (const float*)d_in[3];
  const float* b_ih = (const float*)d_in[4];
  const float* Whh = (const float*)d_in[5];
  const float* b_hh = (const float*)d_in[6];
  const float* ln_w = (const float*)d_in[7];
  const float* ln_b = (const float*)d_in[8];

  char* Ai8 = (char*)d_ws;                                   // 4 MB @ 0
  char* Bi8 = (char*)d_ws + (4u << 20);                      // 8 MB @ 4M
  float* sA = (float*)((char*)d_ws + (12u << 20));           // 8 KB @ 12M
  float* sB = (float*)((char*)d_ws + (12u << 20) + 32768);   // 16 KB
  __half* P0 = (__half*)((char*)d_ws + (16u << 20));         // 16 MB @ 16M
  __half* P1 = (__half*)((char*)d_ws + (32u << 20));         // 16 MB @ 32M

  float* h_out = (float*)d_out;
  float* c_out = (float*)d_out + (size_t)BATCH * H;

  quant_kernel<<<BATCH + NDIM, 256, 0, stream>>>(x, h, Wih, Whh, Ai8, Bi8, sA, sB);
  dim3 g(NDIM / BN, BATCH / BM, 2);
  gemm_kernel<<<g, 256, 0, stream>>>(Ai8, Bi8, sA, sB, P0, P1);
  epilogue_kernel<<<BATCH, 256, 0, stream>>>(P0, P1, c, b_ih, b_hh, ln_w, ln_b, h_out, c_out);
}

// Round 10
// 48.132 us; speedup vs baseline: 1.4734x; 1.0158x over previous
//
#include <hip/hip_runtime.h>
#include <hip/hip_fp16.h>
#include <stdint.h>

#define H 1024
#define BATCH 2048
#define KDIM 2048   // input + hidden concatenated (elements)
#define NDIM 4096   // 4 gates
#define EPS 1e-5f

#define BM 128
#define BN 128
#define BK 128  // i8 elements per K-step (16 KB per matrix tile)

typedef __attribute__((ext_vector_type(4))) int i32x4;

__device__ __forceinline__ float fast_sig(float x) {
  x = fminf(30.f, fmaxf(-30.f, x));
  float e = __expf(x);
  return e / (e + 1.f);
}

__device__ __forceinline__ float fast_tanh(float x) {
  x = fminf(15.f, fmaxf(-15.f, x));
  float e = __expf(2.f * x);
  return (e - 1.f) / (e + 1.f);
}

// ---------------- quant: per-row max-scale int8, concat along K ----------------
__global__ __launch_bounds__(256) void quant_kernel(
    const float* __restrict__ x, const float* __restrict__ h,
    const float* __restrict__ Wih, const float* __restrict__ Whh,
    char* __restrict__ Ai8, char* __restrict__ Bi8,
    float* __restrict__ sA, float* __restrict__ sB) {
  const int r = blockIdx.x;
  const int t = threadIdx.x;
  const float* s0;
  const float* s1;
  char* dst;
  float* sOut;
  if (r < BATCH) {
    s0 = x + (size_t)r * H;
    s1 = h + (size_t)r * H;
    dst = Ai8 + (size_t)r * KDIM;
    sOut = sA + r;
  } else {
    const int rb = r - BATCH;
    s0 = Wih + (size_t)rb * H;
    s1 = Whh + (size_t)rb * H;
    dst = Bi8 + (size_t)rb * KDIM;
    sOut = sB + rb;
  }
  const float* src = (t < 128) ? (s0 + t * 8) : (s1 + (t - 128) * 8);
  float4 v0 = *(const float4*)src;
  float4 v1 = *(const float4*)(src + 4);
  float vv[8] = {v0.x, v0.y, v0.z, v0.w, v1.x, v1.y, v1.z, v1.w};

  float m = 0.f;
#pragma unroll
  for (int i = 0; i < 8; ++i) m = fmaxf(m, fabsf(vv[i]));
#pragma unroll
  for (int off = 32; off > 0; off >>= 1) m = fmaxf(m, __shfl_xor(m, off));
  __shared__ float red[4];
  if ((t & 63) == 0) red[t >> 6] = m;
  __syncthreads();
  m = fmaxf(fmaxf(red[0], red[1]), fmaxf(red[2], red[3]));
  m = fmaxf(m, 1e-20f);
  if (t == 0) *sOut = m * (1.0f / 127.0f);
  const float inv = 127.0f / m;

  char out[8];
#pragma unroll
  for (int i = 0; i < 8; ++i) {
    int qi = (int)rintf(vv[i] * inv);
    qi = max(-127, min(127, qi));
    out[i] = (char)qi;
  }
  *(int2*)(dst + t * 8) = *(const int2*)out;
}

// ---------------- GEMM: int8 MFMA, BK=128, NT=16, no split-K ----------------
__device__ __forceinline__ void load_lds16(const void* g, void* l) {
  __builtin_amdgcn_global_load_lds(
      (const __attribute__((address_space(1))) void*)g,
      (__attribute__((address_space(3))) void*)l, 16, 0, 0);
}

__global__ __launch_bounds__(256, 4) void gemm_kernel(
    const char* __restrict__ A8,  // 2048 x 2048 i8
    const char* __restrict__ B8,  // 4096 x 2048 i8 (B^T layout)
    const float* __restrict__ sA, const float* __restrict__ sB,
    __half* __restrict__ P) {     // 2048 x 4096 fp16
  __shared__ char sAt[BM * BK];  // 16 KB
  __shared__ char sBt[BN * BK];  // 16 KB

  const int tid = threadIdx.x;
  const int wave = tid >> 6;
  const int lane = tid & 63;
  const int m0 = blockIdx.y * BM;
  const int n0 = blockIdx.x * BN;
  const int wr = (wave >> 1) * 64;
  const int wc = (wave & 1) * 64;

  const int frow = lane & 15;
  const int klane = lane >> 4;  // 0..3

  // stage: instr covers 8 rows (8 x 128B = 1 KB): row = base + (lane>>3),
  // phys chunk = lane&7 (linear dest). Source chunk pre-XORed by row&7:
  const int ssrcoff = (((lane & 7) ^ ((lane >> 3) & 7)) << 4);
  // read: logical chunk kc2 = ks*4 + klane; phys = kc2 ^ (row&7); row&7 = frow&7
  const int rxor = (frow & 7);

  i32x4 acc[4][4] = {};

  const int NT = KDIM / BK;  // 16

  for (int t = 0; t < NT; ++t) {
    const int k0 = t * BK;
#pragma unroll
    for (int p = 0; p < 4; ++p) {
      const int rg = wave * 32 + p * 8;  // 8-row group base
      load_lds16(A8 + (size_t)(m0 + rg + (lane >> 3)) * KDIM + k0 + ssrcoff,
                 sAt + rg * BK);
      load_lds16(B8 + (size_t)(n0 + rg + (lane >> 3)) * KDIM + k0 + ssrcoff,
                 sBt + rg * BK);
    }
    asm volatile("s_waitcnt vmcnt(0)" ::: "memory");
    __syncthreads();

#pragma unroll
    for (int ks = 0; ks < 2; ++ks) {
      const int coff = (((ks * 4 + klane) ^ rxor) << 4);
      i32x4 a[4], b[4];
#pragma unroll
      for (int i = 0; i < 4; ++i) {
        a[i] = *(const i32x4*)(sAt + (wr + i * 16 + frow) * BK + coff);
        b[i] = *(const i32x4*)(sBt + (wc + i * 16 + frow) * BK + coff);
      }
      __builtin_amdgcn_s_setprio(1);
#pragma unroll
      for (int i = 0; i < 4; ++i)
#pragma unroll
        for (int j = 0; j < 4; ++j)
          acc[i][j] =
              __builtin_amdgcn_mfma_i32_16x16x64_i8(a[i], b[j], acc[i][j], 0, 0, 0);
      __builtin_amdgcn_s_setprio(0);
    }

    __syncthreads();
  }

  // dequant + store fp16
  const int crow = (lane >> 4) << 2;
  const int ccol = lane & 15;
  float scA[4][4], scB[4];
#pragma unroll
  for (int j = 0; j < 4; ++j) scB[j] = sB[n0 + wc + j * 16 + ccol];
#pragma unroll
  for (int i = 0; i < 4; ++i)
#pragma unroll
    for (int r = 0; r < 4; ++r) scA[i][r] = sA[m0 + wr + i * 16 + crow + r];

#pragma unroll
  for (int i = 0; i < 4; ++i)
#pragma unroll
    for (int j = 0; j < 4; ++j) {
      __half* cp = P + (size_t)(m0 + wr + i * 16 + crow) * NDIM + (n0 + wc + j * 16 + ccol);
#pragma unroll
      for (int r = 0; r < 4; ++r)
        cp[(size_t)r * NDIM] = __float2half((float)acc[i][j][r] * scA[i][r] * scB[j]);
    }
}

// ---------------- epilogue: gates + c update + LN + h -----------------------
__global__ __launch_bounds__(256) void epilogue_kernel(
    const __half* __restrict__ P, const float* __restrict__ c_in,
    const float* __restrict__ b_ih, const float* __restrict__ b_hh,
    const float* __restrict__ ln_w, const float* __restrict__ ln_b,
    float* __restrict__ h_out, float* __restrict__ c_out) {
  const int m = blockIdx.x;
  const int t = threadIdx.x;
  const int j = t << 2;
  const __half* r0 = P + (size_t)m * NDIM;

  float pre[4][4];
#pragma unroll
  for (int g = 0; g < 4; ++g) {
    ushort4 u0 = *(const ushort4*)(r0 + g * H + j);
    float4 bi = *(const float4*)(b_ih + g * H + j);
    float4 bh = *(const float4*)(b_hh + g * H + j);
    pre[g][0] = __half2float(*(__half*)&u0.x) + bi.x + bh.x;
    pre[g][1] = __half2float(*(__half*)&u0.y) + bi.y + bh.y;
    pre[g][2] = __half2float(*(__half*)&u0.z) + bi.z + bh.z;
    pre[g][3] = __half2float(*(__half*)&u0.w) + bi.w + bh.w;
  }
  float4 ci = *(const float4*)(c_in + (size_t)m * H + j);

  float cr[4], vo[4];
  float s = 0.f, q = 0.f;
#pragma unroll
  for (int r = 0; r < 4; ++r) {
    float iv = fast_sig(pre[0][r]);
    float fv = fast_sig(pre[1][r]);
    float ov = fast_sig(pre[2][r]);
    float gv = fast_tanh(pre[3][r]);
    float cv = ((const float*)&ci)[r] * fv + iv * gv;
    cr[r] = cv;
    vo[r] = ov;
    s += cv;
    q += cv * cv;
  }

#pragma unroll
  for (int off = 32; off > 0; off >>= 1) {
    s += __shfl_xor(s, off);
    q += __shfl_xor(q, off);
  }
  __shared__ float red[8];
  const int wv = t >> 6, ln = t & 63;
  if (ln == 0) {
    red[wv] = s;
    red[wv + 4] = q;
  }
  __syncthreads();
  s = red[0] + red[1] + red[2] + red[3];
  q = red[4] + red[5] + red[6] + red[7];
  const float mu = s * (1.f / H);
  const float var = q * (1.f / H) - mu * mu;
  const float rstd = rsqrtf(var + EPS);

  float4 lw = *(const float4*)(ln_w + j);
  float4 lb = *(const float4*)(ln_b + j);
  float4 hov, cov;
#pragma unroll
  for (int r = 0; r < 4; ++r) {
    float cn = (cr[r] - mu) * rstd * ((const float*)&lw)[r] + ((const float*)&lb)[r];
    ((float*)&cov)[r] = cn;
    ((float*)&hov)[r] = vo[r] * fast_tanh(cn);
  }
  *(float4*)(h_out + (size_t)m * H + j) = hov;
  *(float4*)(c_out + (size_t)m * H + j) = cov;
}

extern "C" void kernel_launch(void* const* d_in, const int* in_sizes, int n_in,
                              void* d_out, int out_size, void* d_ws, size_t ws_size,
                              hipStream_t stream) {
  const float* x = (const float*)d_in[0];
  const float* h = (const float*)d_in[1];
  const float* c = (const float*)d_in[2];
  const float* Wih = (const float*)d_in[3];
  const float* b_ih = (const float*)d_in[4];
  const float* Whh = (const float*)d_in[5];
  const float* b_hh = (const float*)d_in[6];
  const float* ln_w = (const float*)d_in[7];
  const float* ln_b = (const float*)d_in[8];

  char* Ai8 = (char*)d_ws;                                   // 4 MB @ 0
  char* Bi8 = (char*)d_ws + (4u << 20);                      // 8 MB @ 4M
  float* sA = (float*)((char*)d_ws + (12u << 20));           // 8 KB @ 12M
  float* sB = (float*)((char*)d_ws + (12u << 20) + 32768);   // 16 KB
  __half* P = (__half*)((char*)d_ws + (16u << 20));          // 16 MB @ 16M

  float* h_out = (float*)d_out;
  float* c_out = (float*)d_out + (size_t)BATCH * H;

  quant_kernel<<<BATCH + NDIM, 256, 0, stream>>>(x, h, Wih, Whh, Ai8, Bi8, sA, sB);
  dim3 g(NDIM / BN, BATCH / BM);
  gemm_kernel<<<g, 256, 0, stream>>>(Ai8, Bi8, sA, sB, P);
  epilogue_kernel<<<BATCH, 256, 0, stream>>>(P, c, b_ih, b_hh, ln_w, ln_b, h_out, c_out);
}

// Round 11
// 47.725 us; speedup vs baseline: 1.4859x; 1.0085x over previous
//
#include <hip/hip_runtime.h>
#include <hip/hip_fp16.h>
#include <stdint.h>

#define H 1024
#define BATCH 2048
#define KDIM 2048   // input + hidden concatenated (elements)
#define NDIM 4096   // 4 gates
#define EPS 1e-5f

#define BM 128
#define BN 128
#define BK 256  // i8 elements per K-step (32 KB per matrix tile)

typedef __attribute__((ext_vector_type(4))) int i32x4;

__device__ __forceinline__ float fast_sig(float x) {
  x = fminf(30.f, fmaxf(-30.f, x));
  float e = __expf(x);
  return e / (e + 1.f);
}

__device__ __forceinline__ float fast_tanh(float x) {
  x = fminf(15.f, fmaxf(-15.f, x));
  float e = __expf(2.f * x);
  return (e - 1.f) / (e + 1.f);
}

// ---------------- quant: per-row max-scale int8, concat along K ----------------
__global__ __launch_bounds__(256) void quant_kernel(
    const float* __restrict__ x, const float* __restrict__ h,
    const float* __restrict__ Wih, const float* __restrict__ Whh,
    char* __restrict__ Ai8, char* __restrict__ Bi8,
    float* __restrict__ sA, float* __restrict__ sB) {
  const int r = blockIdx.x;
  const int t = threadIdx.x;
  const float* s0;
  const float* s1;
  char* dst;
  float* sOut;
  if (r < BATCH) {
    s0 = x + (size_t)r * H;
    s1 = h + (size_t)r * H;
    dst = Ai8 + (size_t)r * KDIM;
    sOut = sA + r;
  } else {
    const int rb = r - BATCH;
    s0 = Wih + (size_t)rb * H;
    s1 = Whh + (size_t)rb * H;
    dst = Bi8 + (size_t)rb * KDIM;
    sOut = sB + rb;
  }
  const float* src = (t < 128) ? (s0 + t * 8) : (s1 + (t - 128) * 8);
  float4 v0 = *(const float4*)src;
  float4 v1 = *(const float4*)(src + 4);
  float vv[8] = {v0.x, v0.y, v0.z, v0.w, v1.x, v1.y, v1.z, v1.w};

  float m = 0.f;
#pragma unroll
  for (int i = 0; i < 8; ++i) m = fmaxf(m, fabsf(vv[i]));
#pragma unroll
  for (int off = 32; off > 0; off >>= 1) m = fmaxf(m, __shfl_xor(m, off));
  __shared__ float red[4];
  if ((t & 63) == 0) red[t >> 6] = m;
  __syncthreads();
  m = fmaxf(fmaxf(red[0], red[1]), fmaxf(red[2], red[3]));
  m = fmaxf(m, 1e-20f);
  if (t == 0) *sOut = m * (1.0f / 127.0f);
  const float inv = 127.0f / m;

  char out[8];
#pragma unroll
  for (int i = 0; i < 8; ++i) {
    int qi = (int)rintf(vv[i] * inv);
    qi = max(-127, min(127, qi));
    out[i] = (char)qi;
  }
  *(int2*)(dst + t * 8) = *(const int2*)out;
}

// ---------------- GEMM: int8 MFMA, BK=256, NT=8, single-buffer --------------
__device__ __forceinline__ void load_lds16(const void* g, void* l) {
  __builtin_amdgcn_global_load_lds(
      (const __attribute__((address_space(1))) void*)g,
      (__attribute__((address_space(3))) void*)l, 16, 0, 0);
}

__global__ __launch_bounds__(256, 2) void gemm_kernel(
    const char* __restrict__ A8,  // 2048 x 2048 i8
    const char* __restrict__ B8,  // 4096 x 2048 i8 (B^T layout)
    const float* __restrict__ sA, const float* __restrict__ sB,
    __half* __restrict__ P) {     // 2048 x 4096 fp16
  __shared__ char sAt[BM * BK];  // 32 KB
  __shared__ char sBt[BN * BK];  // 32 KB

  const int tid = threadIdx.x;
  const int wave = tid >> 6;
  const int lane = tid & 63;
  const int m0 = blockIdx.y * BM;
  const int n0 = blockIdx.x * BN;
  const int wr = (wave >> 1) * 64;
  const int wc = (wave & 1) * 64;

  const int frow = lane & 15;
  const int klane = lane >> 4;  // 0..3
  const int rxor = (frow & 7);

  i32x4 acc[4][4] = {};

  const int NT = KDIM / BK;  // 8

  for (int t = 0; t < NT; ++t) {
    const int k0 = t * BK;
    // stage: each instr covers 4 rows (4 x 256B = 1KB):
    // lane -> row = rg + (lane>>4), phys chunk = lane&15 (linear dest).
    // source chunk pre-XORed by row&7 = 4*(p&1) + (lane>>4).
#pragma unroll
    for (int p = 0; p < 8; ++p) {
      const int rg = wave * 32 + p * 4;  // 4-row group base
      const int srcoff = (((lane & 15) ^ ((4 * (p & 1)) + (lane >> 4))) << 4);
      load_lds16(A8 + (size_t)(m0 + rg + (lane >> 4)) * KDIM + k0 + srcoff,
                 sAt + rg * BK);
      load_lds16(B8 + (size_t)(n0 + rg + (lane >> 4)) * KDIM + k0 + srcoff,
                 sBt + rg * BK);
    }
    asm volatile("s_waitcnt vmcnt(0)" ::: "memory");
    __syncthreads();

#pragma unroll
    for (int ks = 0; ks < 4; ++ks) {
      const int coff = (((ks * 4 + klane) ^ rxor) << 4);
      i32x4 a[4], b[4];
#pragma unroll
      for (int i = 0; i < 4; ++i) {
        a[i] = *(const i32x4*)(sAt + (wr + i * 16 + frow) * BK + coff);
        b[i] = *(const i32x4*)(sBt + (wc + i * 16 + frow) * BK + coff);
      }
      __builtin_amdgcn_s_setprio(1);
#pragma unroll
      for (int i = 0; i < 4; ++i)
#pragma unroll
        for (int j = 0; j < 4; ++j)
          acc[i][j] =
              __builtin_amdgcn_mfma_i32_16x16x64_i8(a[i], b[j], acc[i][j], 0, 0, 0);
      __builtin_amdgcn_s_setprio(0);
    }

    __syncthreads();
  }

  // dequant + store fp16
  const int crow = (lane >> 4) << 2;
  const int ccol = lane & 15;
  float scA[4][4], scB[4];
#pragma unroll
  for (int j = 0; j < 4; ++j) scB[j] = sB[n0 + wc + j * 16 + ccol];
#pragma unroll
  for (int i = 0; i < 4; ++i)
#pragma unroll
    for (int r = 0; r < 4; ++r) scA[i][r] = sA[m0 + wr + i * 16 + crow + r];

#pragma unroll
  for (int i = 0; i < 4; ++i)
#pragma unroll
    for (int j = 0; j < 4; ++j) {
      __half* cp = P + (size_t)(m0 + wr + i * 16 + crow) * NDIM + (n0 + wc + j * 16 + ccol);
#pragma unroll
      for (int r = 0; r < 4; ++r)
        cp[(size_t)r * NDIM] = __float2half((float)acc[i][j][r] * scA[i][r] * scB[j]);
    }
}

// ---------------- epilogue: gates + c update + LN + h -----------------------
__global__ __launch_bounds__(256) void epilogue_kernel(
    const __half* __restrict__ P, const float* __restrict__ c_in,
    const float* __restrict__ b_ih, const float* __restrict__ b_hh,
    const float* __restrict__ ln_w, const float* __restrict__ ln_b,
    float* __restrict__ h_out, float* __restrict__ c_out) {
  const int m = blockIdx.x;
  const int t = threadIdx.x;
  const int j = t << 2;
  const __half* r0 = P + (size_t)m * NDIM;

  float pre[4][4];
#pragma unroll
  for (int g = 0; g < 4; ++g) {
    ushort4 u0 = *(const ushort4*)(r0 + g * H + j);
    float4 bi = *(const float4*)(b_ih + g * H + j);
    float4 bh = *(const float4*)(b_hh + g * H + j);
    pre[g][0] = __half2float(*(__half*)&u0.x) + bi.x + bh.x;
    pre[g][1] = __half2float(*(__half*)&u0.y) + bi.y + bh.y;
    pre[g][2] = __half2float(*(__half*)&u0.z) + bi.z + bh.z;
    pre[g][3] = __half2float(*(__half*)&u0.w) + bi.w + bh.w;
  }
  float4 ci = *(const float4*)(c_in + (size_t)m * H + j);

  float cr[4], vo[4];
  float s = 0.f, q = 0.f;
#pragma unroll
  for (int r = 0; r < 4; ++r) {
    float iv = fast_sig(pre[0][r]);
    float fv = fast_sig(pre[1][r]);
    float ov = fast_sig(pre[2][r]);
    float gv = fast_tanh(pre[3][r]);
    float cv = ((const float*)&ci)[r] * fv + iv * gv;
    cr[r] = cv;
    vo[r] = ov;
    s += cv;
    q += cv * cv;
  }

#pragma unroll
  for (int off = 32; off > 0; off >>= 1) {
    s += __shfl_xor(s, off);
    q += __shfl_xor(q, off);
  }
  __shared__ float red[8];
  const int wv = t >> 6, ln = t & 63;
  if (ln == 0) {
    red[wv] = s;
    red[wv + 4] = q;
  }
  __syncthreads();
  s = red[0] + red[1] + red[2] + red[3];
  q = red[4] + red[5] + red[6] + red[7];
  const float mu = s * (1.f / H);
  const float var = q * (1.f / H) - mu * mu;
  const float rstd = rsqrtf(var + EPS);

  float4 lw = *(const float4*)(ln_w + j);
  float4 lb = *(const float4*)(ln_b + j);
  float4 hov, cov;
#pragma unroll
  for (int r = 0; r < 4; ++r) {
    float cn = (cr[r] - mu) * rstd * ((const float*)&lw)[r] + ((const float*)&lb)[r];
    ((float*)&cov)[r] = cn;
    ((float*)&hov)[r] = vo[r] * fast_tanh(cn);
  }
  *(float4*)(h_out + (size_t)m * H + j) = hov;
  *(float4*)(c_out + (size_t)m * H + j) = cov;
}

extern "C" void kernel_launch(void* const* d_in, const int* in_sizes, int n_in,
                              void* d_out, int out_size, void* d_ws, size_t ws_size,
                              hipStream_t stream) {
  const float* x = (const float*)d_in[0];
  const float* h = (const float*)d_in[1];
  const float* c = (const float*)d_in[2];
  const float* Wih = (const float*)d_in[3];
  const float* b_ih = (const float*)d_in[4];
  const float* Whh = (const float*)d_in[5];
  const float* b_hh = (const float*)d_in[6];
  const float* ln_w = (const float*)d_in[7];
  const float* ln_b = (const float*)d_in[8];

  char* Ai8 = (char*)d_ws;                                   // 4 MB @ 0
  char* Bi8 = (char*)d_ws + (4u << 20);                      // 8 MB @ 4M
  float* sA = (float*)((char*)d_ws + (12u << 20));           // 8 KB @ 12M
  float* sB = (float*)((char*)d_ws + (12u << 20) + 32768);   // 16 KB
  __half* P = (__half*)((char*)d_ws + (16u << 20));          // 16 MB @ 16M

  float* h_out = (float*)d_out;
  float* c_out = (float*)d_out + (size_t)BATCH * H;

  quant_kernel<<<BATCH + NDIM, 256, 0, stream>>>(x, h, Wih, Whh, Ai8, Bi8, sA, sB);
  dim3 g(NDIM / BN, BATCH / BM);
  gemm_kernel<<<g, 256, 0, stream>>>(Ai8, Bi8, sA, sB, P);
  epilogue_kernel<<<BATCH, 256, 0, stream>>>(P, c, b_ih, b_hh, ln_w, ln_b, h_out, c_out);
}